// Round 8
// baseline (604.626 us; speedup 1.0000x reference)
//
#include <hip/hip_runtime.h>
#include <math.h>

// Problem constants (fixed by reference)
#define NF 8
#define NK 16
#define BB 32
#define YY 32
#define XX 32
#define PP 16
#define TT 8
#define YX (YY*XX)     // 1024
#define PT (PP*TT)     // 128
#define YXPT (YX*PT)   // 131072
#define CHUNKS 8
#define COLS_PER_BLOCK (YX/CHUNKS)        // 128
#define TCOLS 16                          // columns per tile
#define NTILES (COLS_PER_BLOCK/TCOLS)     // 8
#define TFLOATS (TCOLS*PT)                // 2048 floats = 8 KB per array per tile

// Workspace layout (float offsets)
#define WPT_OFF   0                          // [NF][NK][PT]         = 16384
#define WYX_OFF   (NF*NK*PT)                 // [NF][YX][NK]         = 131072
#define QMEAN_OFF (WYX_OFF + NF*YX*NK)       // [YXPT]               = 131072
#define ACC_OFF   (QMEAN_OFF + YXPT)         // [CHUNKS][BB*NF*NK]   = 32768
#define INTG_OFF  (ACC_OFF + CHUNKS*BB*NF*NK)// [4][NF*NK]           = 512

// ---------------------------------------------------------------------------
// K1: blocks 0..511  -> qmean (b-split 4 ways + LDS reduce)
//     blocks 512..639-> weight tables, one block per (f,k)
// ---------------------------------------------------------------------------
__global__ __launch_bounds__(256) void k_prep(const float* __restrict__ quad,
                       const float* __restrict__ mean_lat, const float* __restrict__ logstd_lat,
                       const float* __restrict__ mean_lon, const float* __restrict__ logstd_lon,
                       const float* __restrict__ mean_lev, const float* __restrict__ logstd_lev,
                       const float* __restrict__ logtau,
                       float* __restrict__ ws) {
    const int tid = threadIdx.x, bx = blockIdx.x;

    if (bx < 512) {
        __shared__ float4 sm[256];
        const int j4 = bx * 64 + (tid & 63);
        const int bg = tid >> 6;
        const float4* q4 = (const float4*)quad;
        float4 a = make_float4(0.f, 0.f, 0.f, 0.f);
        #pragma unroll
        for (int i = 0; i < 8; ++i) {
            float4 v = q4[(size_t)(bg * 8 + i) * (YXPT / 4) + j4];
            a.x += v.x; a.y += v.y; a.z += v.z; a.w += v.w;
        }
        sm[tid] = a;
        __syncthreads();
        if (tid < 64) {
            float4 r0 = sm[tid], r1 = sm[tid + 64], r2 = sm[tid + 128], r3 = sm[tid + 192];
            float4 r;
            r.x = (r0.x + r1.x + r2.x + r3.x) * (1.f / BB);
            r.y = (r0.y + r1.y + r2.y + r3.y) * (1.f / BB);
            r.z = (r0.z + r1.z + r2.z + r3.z) * (1.f / BB);
            r.w = (r0.w + r1.w + r2.w + r3.w) * (1.f / BB);
            ((float4*)(ws + QMEAN_OFF))[j4] = r;
        }
        return;
    }
    // weight tables: one block per fk, 128 active threads
    const int fk = bx - 512;
    if (tid >= 128) return;
    const int f = fk >> 4, k = fk & 15;
    const float mlat = mean_lat[fk], slat = expf(logstd_lat[fk]);
    const float mlon = mean_lon[fk], slon = expf(logstd_lon[fk]);
    const float mlev = mean_lev[fk], slev = expf(logstd_lev[fk]);
    const float tau  = expf(logtau[fk]) + 1e-4f;

    {   // wpt[fk][tid]:  p = tid>>3, t = tid&7  (coalesced store)
        const int p = tid >> 3, t = tid & 7;
        const float cp = -1.f + 2.f * (float)p / (PP - 1);
        const float zp = (cp - mlev) / slev;
        ws[WPT_OFF + fk * PT + tid] = expf(-0.5f * zp * zp) * expf(-(float)t / tau);
    }
    #pragma unroll
    for (int i = 0; i < 8; ++i) {   // wyx[f][yx][k]
        const int yx = i * 128 + tid;
        const int y = yx >> 5, x = yx & 31;
        const float cy = -1.f + 2.f * (float)y / (YY - 1);
        const float cx = -1.f + 2.f * (float)x / (XX - 1);
        const float zy = (cy - mlat) / slat;
        const float zx = (cx - mlon) / slon;
        ws[WYX_OFF + (f * YX + yx) * NK + k] = expf(-0.5f * zy * zy) * expf(-0.5f * zx * zx);
    }
}

// ---------------------------------------------------------------------------
// K2: quarter-partials of integral[f,k]; block = (fk, quarter), no atomics
// ---------------------------------------------------------------------------
__global__ __launch_bounds__(256) void k_integral(float* __restrict__ ws) {
    const int fk = blockIdx.x >> 2, qr = blockIdx.x & 3;
    const int tid = threadIdx.x;
    const int f = fk >> 4, k = fk & 15;
    const int yx = qr * 256 + tid;
    const float4* w4 = (const float4*)(ws + WPT_OFF + fk * PT);
    const float4* q4 = (const float4*)(ws + QMEAN_OFF + (size_t)yx * PT);
    float s = 0.f;
    #pragma unroll
    for (int j = 0; j < PT / 4; ++j) {
        float4 w = w4[j], q = q4[j];
        s += w.x * q.x + w.y * q.y + w.z * q.z + w.w * q.w;
    }
    float partial = ws[WYX_OFF + (f * YX + yx) * NK + k] * s;
    #pragma unroll
    for (int m = 32; m; m >>= 1) partial += __shfl_xor(partial, m);
    __shared__ float red[4];
    if ((tid & 63) == 0) red[tid >> 6] = partial;
    __syncthreads();
    if (tid == 0)
        ws[INTG_OFF + qr * (NF * NK) + fk] = red[0] + red[1] + red[2] + red[3];
}

// ---------------------------------------------------------------------------
// K3: main contraction, async-DMA version.
// Block = (b, f, chunk of 128 cols); 4 waves. Per-wave double-buffered
// global_load_lds staging of field+quad (16B width), NO barriers in the tile
// loop (per-wave vmcnt waits via inline asm). wyx slice + wpt table staged
// to LDS in the prologue so vmcnt bookkeeping stays clean. R6/R7 showed
// register-rotation pipelines are neutral (compiler collapses them); the
// DMA queue keeps ~48 KB/CU in flight by construction.
// ---------------------------------------------------------------------------
__device__ __forceinline__ void gld16(const float* g, float* l) {
    __builtin_amdgcn_global_load_lds(
        (const __attribute__((address_space(1))) void*)(g),
        (__attribute__((address_space(3))) void*)(l),
        16, 0, 0);
}

__global__ __launch_bounds__(256, 3) void k_main(const float* __restrict__ field,
                                                 const float* __restrict__ quad,
                                                 float* __restrict__ ws) {
    const int bx = blockIdx.x;
    const int f = bx & 7, chunk = (bx >> 3) & 7, b = bx >> 6;
    const int tid = threadIdx.x;
    const int wave = tid >> 6, L = tid & 63;
    const int half = L >> 5, qg = L & 31;
    const int lofs = 4 * L;
    const int WSEG = wave * (TFLOATS / 4);   // wave's 512-float (4-col) segment

    __shared__ float lds[12288];             // 48 KB total
    float* sw   = lds;                        // [128][16] wyx slice   (8 KB)
    float* swpt = lds + 2048;                 // [16][128] wpt table   (8 KB)
    float* ft0  = lds + 4096;                 // tile buffers (8 KB each)
    float* ft1  = lds + 6144;
    float* qt0  = lds + 8192;
    float* qt1  = lds + 10240;

    // ---- prologue: stage sw + swpt (vmem results consumed by ds_writes,
    // so vmcnt is 0 after the barrier) ----
    {
        const float4* srcW = (const float4*)(ws + WYX_OFF + (size_t)(f * YX + chunk * COLS_PER_BLOCK) * NK);
        ((float4*)sw)[tid]       = srcW[tid];
        ((float4*)sw)[tid + 256] = srcW[tid + 256];
        const float4* srcP = (const float4*)(ws + WPT_OFF + (size_t)f * NK * PT);
        ((float4*)swpt)[tid]       = srcP[tid];
        ((float4*)swpt)[tid + 256] = srcP[tid + 256];
    }
    __syncthreads();

    float4 wf[NK];
    #pragma unroll
    for (int k = 0; k < NK; ++k)
        wf[k] = *(const float4*)(swpt + k * PT + 4 * qg);

    float acc[NK];
    #pragma unroll
    for (int k = 0; k < NK; ++k) acc[k] = 0.f;

    // all waves done reading swpt; it is reused as the reduction buffer later
    __syncthreads();

    const float* fgbase = field + (size_t)(b * NF + f) * YXPT + (size_t)(chunk * COLS_PER_BLOCK) * PT;
    const float* qgbase = quad + (size_t)b * YXPT + (size_t)(chunk * COLS_PER_BLOCK) * PT;

    // DMA one tile's wave-segment: 2 field + 2 quad instrs (1 KB each)
    #define DMA_TILE(t, fb, qb)                                                     \
        do {                                                                        \
            gld16(fgbase + (t) * TFLOATS + WSEG + 0 * 256 + lofs, (fb) + WSEG + 0 * 256 + lofs); \
            gld16(fgbase + (t) * TFLOATS + WSEG + 1 * 256 + lofs, (fb) + WSEG + 1 * 256 + lofs); \
            gld16(qgbase + (t) * TFLOATS + WSEG + 0 * 256 + lofs, (qb) + WSEG + 0 * 256 + lofs); \
            gld16(qgbase + (t) * TFLOATS + WSEG + 1 * 256 + lofs, (qb) + WSEG + 1 * 256 + lofs); \
        } while (0)

    #define COMP_TILE(t, fb, qb)                                                    \
        do {                                                                        \
            _Pragma("unroll")                                                       \
            for (int j = 0; j < 2; ++j) {                                           \
                float4 fv = *(const float4*)((fb) + WSEG + j * 256 + lofs);         \
                float4 qv = *(const float4*)((qb) + WSEG + j * 256 + lofs);         \
                const int c = (t) * TCOLS + wave * 4 + 2 * j + half;                \
                const float4* wvp = (const float4*)(sw + c * NK);                   \
                float4 a0 = wvp[0], a1 = wvp[1], a2 = wvp[2], a3 = wvp[3];          \
                float wv[NK];                                                       \
                *(float4*)(wv + 0)  = a0;                                           \
                *(float4*)(wv + 4)  = a1;                                           \
                *(float4*)(wv + 8)  = a2;                                           \
                *(float4*)(wv + 12) = a3;                                           \
                float4 ga;                                                          \
                ga.x = fv.x * qv.x; ga.y = fv.y * qv.y;                             \
                ga.z = fv.z * qv.z; ga.w = fv.w * qv.w;                             \
                _Pragma("unroll")                                                   \
                for (int k = 0; k < NK; ++k) {                                      \
                    float d = ga.x * wf[k].x;                                       \
                    d = fmaf(ga.y, wf[k].y, d);                                     \
                    d = fmaf(ga.z, wf[k].z, d);                                     \
                    d = fmaf(ga.w, wf[k].w, d);                                     \
                    acc[k] = fmaf(wv[k], d, acc[k]);                                \
                }                                                                   \
            }                                                                       \
        } while (0)

    #define WAITV4 asm volatile("s_waitcnt vmcnt(4)" ::: "memory")
    #define WAITV0 asm volatile("s_waitcnt vmcnt(0)" ::: "memory")

    // tile pipeline: issue 0,1; per step wait-oldest-4, compute, refill.
    DMA_TILE(0, ft0, qt0);
    DMA_TILE(1, ft1, qt1);                 // 8 outstanding
    WAITV4; COMP_TILE(0, ft0, qt0); DMA_TILE(2, ft0, qt0);
    WAITV4; COMP_TILE(1, ft1, qt1); DMA_TILE(3, ft1, qt1);
    WAITV4; COMP_TILE(2, ft0, qt0); DMA_TILE(4, ft0, qt0);
    WAITV4; COMP_TILE(3, ft1, qt1); DMA_TILE(5, ft1, qt1);
    WAITV4; COMP_TILE(4, ft0, qt0); DMA_TILE(6, ft0, qt0);
    WAITV4; COMP_TILE(5, ft1, qt1); DMA_TILE(7, ft1, qt1);
    WAITV4; COMP_TILE(6, ft0, qt0);
    WAITV0; COMP_TILE(7, ft1, qt1);

    // wave butterfly -> cross-wave LDS (reusing swpt) -> one store per k
    float* red = swpt;
    #pragma unroll
    for (int k = 0; k < NK; ++k) {
        float v = acc[k];
        v += __shfl_xor(v, 32); v += __shfl_xor(v, 16); v += __shfl_xor(v, 8);
        v += __shfl_xor(v, 4);  v += __shfl_xor(v, 2);  v += __shfl_xor(v, 1);
        if (L == 0) red[wave * NK + k] = v;
    }
    __syncthreads();
    if (tid < NK) {
        float s2 = red[0 * NK + tid] + red[1 * NK + tid] + red[2 * NK + tid] + red[3 * NK + tid];
        ws[ACC_OFF + chunk * (BB * NF * NK) + (b * NF + f) * NK + tid] = s2;
    }
}

// ---------------------------------------------------------------------------
// K4: out[b,f,k] = sum_c accP[c] / (1e-4 + sum_q intgP[q])
// ---------------------------------------------------------------------------
__global__ void k_final(const float* __restrict__ ws, float* __restrict__ out) {
    int i = blockIdx.x * 256 + threadIdx.x;
    if (i >= BB * NF * NK) return;
    float a = 0.f;
    #pragma unroll
    for (int c = 0; c < CHUNKS; ++c) a += ws[ACC_OFF + c * (BB * NF * NK) + i];
    const int fk = i & (NF * NK - 1);
    float g = 1e-4f;
    #pragma unroll
    for (int q = 0; q < 4; ++q) g += ws[INTG_OFF + q * (NF * NK) + fk];
    out[i] = a / g;
}

extern "C" void kernel_launch(void* const* d_in, const int* in_sizes, int n_in,
                              void* d_out, int out_size, void* d_ws, size_t ws_size,
                              hipStream_t stream) {
    const float* field = (const float*)d_in[0];
    const float* quad  = (const float*)d_in[1];
    float* ws = (float*)d_ws;

    k_prep<<<640, 256, 0, stream>>>(quad,
        (const float*)d_in[2], (const float*)d_in[3],
        (const float*)d_in[4], (const float*)d_in[5],
        (const float*)d_in[6], (const float*)d_in[7],
        (const float*)d_in[8], ws);
    k_integral<<<NF * NK * 4, 256, 0, stream>>>(ws);
    k_main<<<BB * NF * CHUNKS, 256, 0, stream>>>(field, quad, ws);
    k_final<<<(BB * NF * NK + 255) / 256, 256, 0, stream>>>(ws, (float*)d_out);
}